// Round 4
// baseline (433.552 us; speedup 1.0000x reference)
//
#include <hip/hip_runtime.h>
#include <hip/hip_bf16.h>

constexpr int kB = 8, kN = 256, kD = 16, kHID = 256, kH = 128, kDH = 64, kdh = 32;
constexpr int kBN = kB * kN;          // 2048 rows
constexpr int kP  = kBN * kD;         // 32768 points

__device__ __forceinline__ float b2f(__hip_bfloat16 v) { return __bfloat162float(v); }
__device__ __forceinline__ __hip_bfloat16 f2b(float v) { return __float2bfloat16(v); }
__device__ __forceinline__ unsigned short f2bs(float v) {
    __hip_bfloat16 h = __float2bfloat16(v);
    return *(unsigned short*)&h;
}

__device__ __forceinline__ float tanh_fast(float v) {
    float e = __expf(2.f * v);
    return 1.f - 2.f * __builtin_amdgcn_rcpf(e + 1.f);
}

typedef short s8v  __attribute__((ext_vector_type(8)));   // 8 bf16 = 4 VGPRs
typedef float f4v  __attribute__((ext_vector_type(4)));
#define MFMA(a, b, c) __builtin_amdgcn_mfma_f32_16x16x32_bf16((a), (b), (c), 0, 0, 0)

struct KParams {
    const float *t, *x;
    const float *q_b0, *k_b0, *v_b0, *q_b1, *k_b1, *v_b1, *k_b2, *v_b2, *q_b2;
    const float *p_w, *p_b;
    const float *d_w0, *d_b0, *d_b1, *d_b2, *d_w3, *d_b3, *d_w1, *d_w2;
    const float *k_w0, *k_w1, *k_w2, *v_w0, *v_w1, *v_w2, *q_w0, *q_w1, *q_w2;
    __hip_bfloat16 *pwf, *w0f, *w1f, *w2f;
    __hip_bfloat16 *k0f, *k1f, *k2f, *v0f, *v1f, *v2f, *q0f, *q1f, *q2f;
    __hip_bfloat16 *kbufF, *vbufF, *h1qF, *obuf;
    unsigned *bar;
    float *out;
};

// ---------- device-scope global barrier (all kGrid blocks co-resident) ----------
constexpr unsigned kGrid = 512;

__device__ __forceinline__ void gbar(unsigned* bar, int idx)
{
    __syncthreads();
    if (threadIdx.x == 0) {
        __threadfence();   // release all prior stores to device scope
        __hip_atomic_fetch_add(&bar[idx], 1u, __ATOMIC_ACQ_REL, __HIP_MEMORY_SCOPE_AGENT);
        unsigned v; long spins = 0;
        do {
            v = __hip_atomic_load(&bar[idx], __ATOMIC_ACQUIRE, __HIP_MEMORY_SCOPE_AGENT);
            if (++spins > 5000000) break;           // failsafe: never hang the container
            if (v < kGrid) __builtin_amdgcn_s_sleep(2);
        } while (v < kGrid);
        __threadfence();   // acquire: invalidate stale L1/L2 before consuming
    }
    __syncthreads();
}

// ---------- prep: swizzle one weight tile into MFMA B-fragment layout ----------
// Tile map: 0..15 pwf | 16..47 w0f | 48..175 w1f | 176..239 w2f | 240..255 k0f
// 256..271 v0f | 272..287 q0f | 288..415 k1f | 416..543 v1f | 544..671 q1f
// 672..735 k2f | 736..799 v2f | 800..1823 q2f
__device__ __forceinline__ void prep_tile(const KParams& P, int tile, int lane)
{
    const float* src; __hip_bfloat16* dst; int N, NT, local, Kreal = 1 << 30, mask = 0;
    if (tile < 16)        { src = P.p_w;        dst = P.pwf; N = 64;   NT = 4;   local = tile; }
    else if (tile < 48)   { src = P.d_w0 + 512; dst = P.w0f; N = 256;  NT = 16;  local = tile - 16; }
    else if (tile < 176)  { src = P.d_w1;       dst = P.w1f; N = 256;  NT = 16;  local = tile - 48; }
    else if (tile < 240)  { src = P.d_w2;       dst = P.w2f; N = 128;  NT = 8;   local = tile - 176; }
    else if (tile < 256)  { src = P.k_w0;       dst = P.k0f; N = 256;  NT = 16;  local = tile - 240; Kreal = 16; }
    else if (tile < 272)  { src = P.v_w0;       dst = P.v0f; N = 256;  NT = 16;  local = tile - 256; Kreal = 16; }
    else if (tile < 288)  { src = P.q_w0;       dst = P.q0f; N = 256;  NT = 16;  local = tile - 272; Kreal = 16; mask = 1; }
    else if (tile < 416)  { src = P.k_w1;       dst = P.k1f; N = 256;  NT = 16;  local = tile - 288; }
    else if (tile < 544)  { src = P.v_w1;       dst = P.v1f; N = 256;  NT = 16;  local = tile - 416; }
    else if (tile < 672)  { src = P.q_w1;       dst = P.q1f; N = 256;  NT = 16;  local = tile - 544; mask = 2; }
    else if (tile < 736)  { src = P.k_w2;       dst = P.k2f; N = 128;  NT = 8;   local = tile - 672; }
    else if (tile < 800)  { src = P.v_w2;       dst = P.v2f; N = 128;  NT = 8;   local = tile - 736; }
    else                  { src = P.q_w2;       dst = P.q2f; N = 2048; NT = 128; local = tile - 800; mask = 3; }
    const int kt = local / NT, nt = local % NT;
    const int row0 = kt * 32 + (lane >> 4) * 8;
    const int col  = nt * 16 + (lane & 15);
    __hip_bfloat16* o = dst + ((size_t)local * 64 + lane) * 8;
    #pragma unroll
    for (int j = 0; j < 8; ++j) {
        const int r = row0 + j;
        float w = (r < Kreal) ? src[(size_t)r * N + col] : 0.f;
        if (mask == 1 && !((col % 15) >= r))        w = 0.f;
        if (mask == 2 && !((col % 15) >= (r % 15))) w = 0.f;
        if (mask == 3 && !((col >> 7) > (r % 15)))  w = 0.f;
        o[j] = f2b(w);
    }
}

// ---------- mlp: one path per block (0=k,1=v,2=q), 32-row tile. smem: 36352 B ----------
__device__ __forceinline__ void mlp_body(const KParams& P, char* smem, int blk)
{
    constexpr int SA = 264;
    constexpr int SX = 40;
    __hip_bfloat16* xin  = (__hip_bfloat16*)smem;
    __hip_bfloat16* bufA = (__hip_bfloat16*)(smem + 2560);
    __hip_bfloat16* bufB = (__hip_bfloat16*)(smem + 19456);

    const int tid  = threadIdx.x;
    const int wv   = tid >> 6, lane = tid & 63;
    const int lx   = lane & 15, quad = lane >> 4;
    const int path = blk >> 6;
    const int r0   = (blk & 63) * 32;

    auto ldA = [&](const __hip_bfloat16* buf, int stride, int m0, int k0) -> s8v {
        return *(const s8v*)(buf + (m0 + lx) * stride + k0 + quad * 8);
    };
    auto ldB = [&](const __hip_bfloat16* wf, int NT, int kt, int nt) -> s8v {
        return *(const s8v*)(wf + (((size_t)(kt * NT + nt) * 64 + lane) << 3));
    };

    for (int idx = tid; idx < 1024; idx += 256) {
        const int row = idx >> 5, c = idx & 31;
        xin[row * SX + c] = f2b(c < 16 ? P.x[(r0 + row) * kD + c] : 0.f);
    }

    const __hip_bfloat16* F0[3] = { P.k0f, P.v0f, P.q0f };
    const __hip_bfloat16* F1[3] = { P.k1f, P.v1f, P.q1f };
    const __hip_bfloat16* F2[2] = { P.k2f, P.v2f };
    const float* Ba0[3] = { P.k_b0, P.v_b0, P.q_b0 };
    const float* Ba1[3] = { P.k_b1, P.v_b1, P.q_b1 };
    const float* Ba2[2] = { P.k_b2, P.v_b2 };

    __syncthreads();

    {   // L0: M=32, N=256, K=32 (padded)
        f4v acc[4][2] = {};
        const s8v a0 = ldA(xin, SX, 0, 0);
        const s8v a1 = ldA(xin, SX, 16, 0);
        #pragma unroll
        for (int j = 0; j < 4; ++j) {
            s8v b = ldB(F0[path], 16, 0, wv * 4 + j);
            acc[j][0] = MFMA(a0, b, acc[j][0]);
            acc[j][1] = MFMA(a1, b, acc[j][1]);
        }
        #pragma unroll
        for (int j = 0; j < 4; ++j) {
            const int n = (wv * 4 + j) * 16 + lx;
            const float bb = Ba0[path][n];
            #pragma unroll
            for (int mt = 0; mt < 2; ++mt)
            #pragma unroll
            for (int r = 0; r < 4; ++r) {
                const float v = acc[j][mt][r] + bb;
                const float z = (path == 2) ? fmaxf(v, 0.f) : tanh_fast(v);
                bufA[(mt * 16 + quad * 4 + r) * SA + n] = f2b(z);
            }
        }
    }
    __syncthreads();

    {   // L1: M=32, N=256, K=256
        f4v acc[4][2] = {};
        #pragma unroll
        for (int kt = 0; kt < 8; ++kt) {
            const s8v a0 = ldA(bufA, SA, 0, kt * 32);
            const s8v a1 = ldA(bufA, SA, 16, kt * 32);
            #pragma unroll
            for (int j = 0; j < 4; ++j) {
                s8v b = ldB(F1[path], 16, kt, wv * 4 + j);
                acc[j][0] = MFMA(a0, b, acc[j][0]);
                acc[j][1] = MFMA(a1, b, acc[j][1]);
            }
        }
        #pragma unroll
        for (int j = 0; j < 4; ++j) {
            const int n = (wv * 4 + j) * 16 + lx;
            const float bb = Ba1[path][n];
            #pragma unroll
            for (int mt = 0; mt < 2; ++mt)
            #pragma unroll
            for (int r = 0; r < 4; ++r) {
                const int m = mt * 16 + quad * 4 + r;
                const float v = acc[j][mt][r] + bb;
                if (path == 2) {
                    // A-fragment-packed h1q
                    const int kt2 = (wv * 4 + j) >> 1;
                    const int q2  = ((wv * 4 + j) & 1) * 2 + (lx >> 3);
                    P.h1qF[(size_t)(((r0 >> 4) + mt) * 8 + kt2) * 512
                         + (q2 * 16 + quad * 4 + r) * 8 + (lx & 7)] = f2b(fmaxf(v, 0.f));
                } else {
                    bufB[m * SA + n] = f2b(tanh_fast(v));
                }
            }
        }
    }
    if (path == 2) return;
    __syncthreads();

    {   // L2: M=32, N=128, K=256, linear -> fragment-packed kbufF / vbufF
        f4v acc[2][2] = {};
        #pragma unroll
        for (int kt = 0; kt < 8; ++kt) {
            const s8v a0 = ldA(bufB, SA, 0, kt * 32);
            const s8v a1 = ldA(bufB, SA, 16, kt * 32);
            #pragma unroll
            for (int j = 0; j < 2; ++j) {
                s8v b = ldB(F2[path], 8, kt, wv * 2 + j);
                acc[j][0] = MFMA(a0, b, acc[j][0]);
                acc[j][1] = MFMA(a1, b, acc[j][1]);
            }
        }
        const int bidx = r0 >> 8;
        const int ktv  = (r0 >> 5) & 7;
        #pragma unroll
        for (int j = 0; j < 2; ++j) {
            const int n  = (wv * 2 + j) * 16 + lx;
            const float bb = Ba2[path][n];
            const int hd = n >> 5;
            #pragma unroll
            for (int mt = 0; mt < 2; ++mt)
            #pragma unroll
            for (int r = 0; r < 4; ++r) {
                const int gr = r0 + mt * 16 + quad * 4 + r;
                const __hip_bfloat16 hv = f2b(acc[j][mt][r] + bb);
                if (path == 0) {
                    const int mtg = (gr >> 4) & 15;
                    P.kbufF[(size_t)(((bidx * 4 + hd) * 16 + mtg) * 64
                          + ((n & 31) >> 3) * 16 + (gr & 15)) * 8 + (lx & 7)] = hv;
                } else {
                    const int m5 = gr & 31;
                    P.vbufF[(size_t)((((bidx * 4 + hd) * 2 + ((n >> 4) & 1)) * 8 + ktv) * 64
                          + (m5 >> 3) * 16 + lx) * 8 + (m5 & 7)] = hv;
                }
            }
        }
    }
}

// ---------- attn: fused Q-projection + attention, one (b,d,hd) per block. smem: 54272 B ----------
__device__ __forceinline__ void attn_body(const KParams& P, char* smem, int blk)
{
    constexpr int SP = 264;
    constexpr int QP = 40;
    short* Pl = (short*)smem;                     // 4*16*SP shorts = 33792 B
    short* Qw = (short*)(smem + 33792);           // 256*QP shorts = 20480 B

    const int hd = blk & 3;
    const int d  = (blk >> 2) & 15;
    const int b  = blk >> 6;

    const int wv   = threadIdx.x >> 6;
    const int lane = threadIdx.x & 63;
    const int lx = lane & 15, quad = lane >> 4;
    short* Pw = Pl + wv * 16 * SP;

    const short* hq = (const short*)P.h1qF;
    const short* kb = (const short*)P.kbufF;
    const short* vb = (const short*)P.vbufF;
    const int bh = b * 4 + hd;

    // fused Q-GEMM: M=64 (this wave's rows), N=32, K=256
    f4v qacc[4][2] = {};
    #pragma unroll
    for (int kt = 0; kt < 8; ++kt) {
        const s8v b0 = *(const s8v*)(P.q2f + (((size_t)(kt * 128 + d * 8 + hd * 2 + 0) * 64 + lane) << 3));
        const s8v b1 = *(const s8v*)(P.q2f + (((size_t)(kt * 128 + d * 8 + hd * 2 + 1) * 64 + lane) << 3));
        #pragma unroll
        for (int mt = 0; mt < 4; ++mt) {
            const s8v a = *(const s8v*)(hq + ((size_t)((b * 16 + wv * 4 + mt) * 8 + kt) * 512 + lane * 8));
            qacc[mt][0] = MFMA(a, b0, qacc[mt][0]);
            qacc[mt][1] = MFMA(a, b1, qacc[mt][1]);
        }
    }

    // K/V fragments: fully coalesced 16B/lane loads
    s8v kfrag[16];
    #pragma unroll
    for (int mt = 0; mt < 16; ++mt)
        kfrag[mt] = *(const s8v*)(kb + ((size_t)(bh * 16 + mt) * 64 + lane) * 8);
    s8v vfrag[2][8];
    #pragma unroll
    for (int ntv = 0; ntv < 2; ++ntv)
    #pragma unroll
    for (int kt = 0; kt < 8; ++kt)
        vfrag[ntv][kt] = *(const s8v*)(vb + ((size_t)((bh * 2 + ntv) * 8 + kt) * 64 + lane) * 8);

    {   // Q epilogue: bias + 1/sqrt(dh) scale -> LDS
        const float scale = 0.17677669529663687f;
        #pragma unroll
        for (int jn = 0; jn < 2; ++jn) {
            const float bb = P.q_b2[d * 128 + hd * 32 + jn * 16 + lx];
            #pragma unroll
            for (int mt = 0; mt < 4; ++mt)
            #pragma unroll
            for (int r = 0; r < 4; ++r) {
                const int lrow = wv * 64 + mt * 16 + quad * 4 + r;
                Qw[lrow * QP + jn * 16 + lx] = (short)f2bs((qacc[mt][jn][r] + bb) * scale);
            }
        }
    }
    __syncthreads();

    const float LOG2E = 1.4426950408889634f;

    for (int mi = 0; mi < 4; ++mi) {
        const int q0 = wv * 64 + mi * 16;

        const s8v qfrag = *(const s8v*)(Qw + (q0 + lx) * QP + quad * 8);

        f4v acc[16];
        #pragma unroll
        for (int mt = 0; mt < 16; ++mt) acc[mt] = f4v{0.f, 0.f, 0.f, 0.f};
        #pragma unroll
        for (int mt = 0; mt < 16; ++mt) acc[mt] = MFMA(kfrag[mt], qfrag, acc[mt]);

        const int qg = q0 + lx;
        float mx = -3.0e38f;
        #pragma unroll
        for (int mt = 0; mt < 16; ++mt)
        #pragma unroll
        for (int r = 0; r < 4; ++r) {
            const int key = mt * 16 + quad * 4 + r;
            float s = (key == qg) ? -3.0e38f : acc[mt][r];
            acc[mt][r] = s;
            mx = fmaxf(mx, s);
        }
        mx = fmaxf(mx, __shfl_xor(mx, 16, 64));
        mx = fmaxf(mx, __shfl_xor(mx, 32, 64));

        const float nmxc = -mx * LOG2E;
        float l = 0.f;
        #pragma unroll
        for (int mt = 0; mt < 16; ++mt)
        #pragma unroll
        for (int r = 0; r < 4; ++r) {
            float p = exp2f(__builtin_fmaf(acc[mt][r], LOG2E, nmxc));
            acc[mt][r] = p;
            l += p;
        }
        l += __shfl_xor(l, 16, 64);
        l += __shfl_xor(l, 32, 64);

        #pragma unroll
        for (int mt = 0; mt < 16; ++mt) {
            unsigned short h0 = f2bs(acc[mt][0]);
            unsigned short h1 = f2bs(acc[mt][1]);
            unsigned short h2 = f2bs(acc[mt][2]);
            unsigned short h3 = f2bs(acc[mt][3]);
            uint2 w;
            w.x = (unsigned int)h0 | ((unsigned int)h1 << 16);
            w.y = (unsigned int)h2 | ((unsigned int)h3 << 16);
            *(uint2*)(Pw + lx * SP + mt * 16 + quad * 4) = w;
        }
        __asm__ volatile("s_waitcnt lgkmcnt(0)" ::: "memory");

        f4v av[2] = { f4v{0.f,0.f,0.f,0.f}, f4v{0.f,0.f,0.f,0.f} };
        #pragma unroll
        for (int kt = 0; kt < 8; ++kt) {
            s8v a = *(const s8v*)(Pw + lx * SP + kt * 32 + quad * 8);
            av[0] = MFMA(a, vfrag[0][kt], av[0]);
            av[1] = MFMA(a, vfrag[1][kt], av[1]);
        }
        __asm__ volatile("s_waitcnt lgkmcnt(0)" ::: "memory");

        #pragma unroll
        for (int r = 0; r < 4; ++r) {
            const float lr = __shfl(l, quad * 4 + r, 64);
            const float inv = __builtin_amdgcn_rcpf(lr);
            const int qrow = q0 + quad * 4 + r;
            #pragma unroll
            for (int ntv = 0; ntv < 2; ++ntv) {
                P.obuf[((size_t)((b * 256 + qrow) * 16 + d)) * 128 + hd * 32 + ntv * 16 + lx]
                    = f2b(av[ntv][r] * inv);
            }
        }
    }
}

// ---------- dim: dimwise net + exact Jacobian, 32 points per tile. smem: 72320 B ----------
__device__ __forceinline__ void dim_body(const KParams& P, char* smem, int tile)
{
    constexpr int SA = 264;
    constexpr int SO = 136;
    constexpr int SH = 72;
    __hip_bfloat16* bufA = (__hip_bfloat16*)smem;             // 64*SA*2 = 33792
    __hip_bfloat16* bufB = (__hip_bfloat16*)(smem + 33792);   // 64*SA*2 = 33792
    __hip_bfloat16* bufH = (__hip_bfloat16*)(smem + 67584);   // 32*SH*2 = 4608
    float* xvs = (float*)(smem + 72192);                      // 128

    const int tid  = threadIdx.x;
    const int wv   = tid >> 6, lane = tid & 63;
    const int lx   = lane & 15, quad = lane >> 4;
    const int p0   = tile * 32;
    const float tval = P.t[0];

    auto ldA = [&](const __hip_bfloat16* buf, int stride, int m0, int k0) -> s8v {
        return *(const s8v*)(buf + (m0 + lx) * stride + k0 + quad * 8);
    };
    auto ldBf = [&](const __hip_bfloat16* wf, int NT, int kt, int nt) -> s8v {
        return *(const s8v*)(wf + (((size_t)(kt * NT + nt) * 64 + lane) << 3));
    };

    // stage obuf rows (32 x 128) -> bufA stride SO
    for (int idx = tid; idx < 512; idx += 256) {
        const int row = idx >> 4, ch = idx & 15;
        *(f4v*)(bufA + row * SO + ch * 8) = *(const f4v*)(P.obuf + (size_t)(p0 + row) * kH + ch * 8);
    }
    if (tid < 32) xvs[tid] = P.x[p0 + tid];
    __syncthreads();

    {   // hfeat: M=32, N=64, K=128
        f4v acc0 = {}, acc1 = {};
        #pragma unroll
        for (int ktile = 0; ktile < 4; ++ktile) {
            s8v b  = ldBf(P.pwf, 4, ktile, wv);
            s8v a0 = ldA(bufA, SO, 0,  ktile * 32);
            s8v a1 = ldA(bufA, SO, 16, ktile * 32);
            acc0 = MFMA(a0, b, acc0);
            acc1 = MFMA(a1, b, acc1);
        }
        const int n = wv * 16 + lx;
        const float bb = P.p_b[n];
        #pragma unroll
        for (int r = 0; r < 4; ++r) {
            bufH[(quad * 4 + r) * SH + n]      = f2b(acc0[r] + bb);
            bufH[(quad * 4 + r + 16) * SH + n] = f2b(acc1[r] + bb);
        }
    }
    __syncthreads();

    {   // L0: M=32, N=256, K=64 -> bufB (z rows 0-31, zd rows 32-63)
        f4v acc[4][2] = {};
        #pragma unroll
        for (int ktile = 0; ktile < 2; ++ktile) {
            s8v a0 = ldA(bufH, SH, 0,  ktile * 32);
            s8v a1 = ldA(bufH, SH, 16, ktile * 32);
            #pragma unroll
            for (int j = 0; j < 4; ++j) {
                s8v b = ldBf(P.w0f, 16, ktile, wv * 4 + j);
                acc[j][0] = MFMA(a0, b, acc[j][0]);
                acc[j][1] = MFMA(a1, b, acc[j][1]);
            }
        }
        #pragma unroll
        for (int j = 0; j < 4; ++j) {
            const int n = (wv * 4 + j) * 16 + lx;
            const float base = P.d_b0[n] + tval * P.d_w0[n];
            const float wx   = P.d_w0[256 + n];
            #pragma unroll
            for (int mt = 0; mt < 2; ++mt)
            #pragma unroll
            for (int r = 0; r < 4; ++r) {
                const int m = mt * 16 + quad * 4 + r;
                const float z = tanh_fast(acc[j][mt][r] + base + xvs[m] * wx);
                bufB[m * SA + n]        = f2b(z);
                bufB[(m + 32) * SA + n] = f2b((1.f - z * z) * wx);
            }
        }
    }
    __syncthreads();

    {   // L1: M=64 (32 fwd + 32 tgt), N=256, K=256 -> bufA
        f4v acc[4][4] = {};
        #pragma unroll
        for (int ktile = 0; ktile < 8; ++ktile) {
            s8v a0 = ldA(bufB, SA, 0,  ktile * 32);
            s8v a1 = ldA(bufB, SA, 16, ktile * 32);
            s8v a2 = ldA(bufB, SA, 32, ktile * 32);
            s8v a3 = ldA(bufB, SA, 48, ktile * 32);
            #pragma unroll
            for (int j = 0; j < 4; ++j) {
                s8v b = ldBf(P.w1f, 16, ktile, wv * 4 + j);
                acc[j][0] = MFMA(a0, b, acc[j][0]);
                acc[j][1] = MFMA(a1, b, acc[j][1]);
                acc[j][2] = MFMA(a2, b, acc[j][2]);
                acc[j][3] = MFMA(a3, b, acc[j][3]);
            }
        }
        #pragma unroll
        for (int j = 0; j < 4; ++j) {
            const int n = (wv * 4 + j) * 16 + lx;
            const float b1 = P.d_b1[n];
            #pragma unroll
            for (int mt = 0; mt < 2; ++mt)
            #pragma unroll
            for (int r = 0; r < 4; ++r) {
                const int m = mt * 16 + quad * 4 + r;
                const float z  = tanh_fast(acc[j][mt][r] + b1);
                const float zd = (1.f - z * z) * acc[j][mt + 2][r];
                bufA[m * SA + n]        = f2b(z);
                bufA[(m + 32) * SA + n] = f2b(zd);
            }
        }
    }
    __syncthreads();

    {   // L2: M=64, N=128, K=256 -> bufB (stride SO)
        f4v acc[2][4] = {};
        #pragma unroll
        for (int ktile = 0; ktile < 8; ++ktile) {
            s8v a0 = ldA(bufA, SA, 0,  ktile * 32);
            s8v a1 = ldA(bufA, SA, 16, ktile * 32);
            s8v a2 = ldA(bufA, SA, 32, ktile * 32);
            s8v a3 = ldA(bufA, SA, 48, ktile * 32);
            #pragma unroll
            for (int j = 0; j < 2; ++j) {
                s8v b = ldBf(P.w2f, 8, ktile, wv * 2 + j);
                acc[j][0] = MFMA(a0, b, acc[j][0]);
                acc[j][1] = MFMA(a1, b, acc[j][1]);
                acc[j][2] = MFMA(a2, b, acc[j][2]);
                acc[j][3] = MFMA(a3, b, acc[j][3]);
            }
        }
        #pragma unroll
        for (int j = 0; j < 2; ++j) {
            const int n = (wv * 2 + j) * 16 + lx;
            const float b2 = P.d_b2[n];
            #pragma unroll
            for (int mt = 0; mt < 2; ++mt)
            #pragma unroll
            for (int r = 0; r < 4; ++r) {
                const int m = mt * 16 + quad * 4 + r;
                const float z  = tanh_fast(acc[j][mt][r] + b2);
                const float zd = (1.f - z * z) * acc[j][mt + 2][r];
                bufB[m * SO + n]        = f2b(z);
                bufB[(m + 32) * SO + n] = f2b(zd);
            }
        }
    }
    __syncthreads();

    {   // L3 reduce: 32 points x 8 threads, 16 cols each
        const int p = tid >> 3, s = tid & 7;
        float yv = 0.f, jv = 0.f;
        #pragma unroll
        for (int i = 0; i < 16; ++i) {
            const int n = s + i * 8;
            const float w = P.d_w3[n];
            yv += b2f(bufB[p * SO + n]) * w;
            jv += b2f(bufB[(p + 32) * SO + n]) * w;
        }
        #pragma unroll
        for (int off = 4; off > 0; off >>= 1) {
            yv += __shfl_down(yv, off, 8);
            jv += __shfl_down(jv, off, 8);
        }
        if (s == 0) {
            P.out[p0 + p]      = yv + P.d_b3[0];
            P.out[kP + p0 + p] = jv;
        }
    }
}

// ---------- init: zero the barrier counters (workspace is re-poisoned每 iteration) ----------
__global__ __launch_bounds__(64) void init_kernel(KParams P)
{
    if (threadIdx.x < 8) P.bar[threadIdx.x] = 0u;
    __threadfence();
}

// ---------- fused persistent kernel: 512 blocks = 2/CU co-resident (LDS 72.5 KB) ----------
__global__ __launch_bounds__(256, 2) void fused_kernel(KParams P)
{
    __shared__ __align__(16) char smem[72448];
    const int wv   = threadIdx.x >> 6;
    const int lane = threadIdx.x & 63;
    const int blk  = blockIdx.x;

    // Phase 0: prep mlp-path weight fragments (tiles 240..799) on blocks 0..139
    {
        const int s = blk * 4 + wv;
        if (s < 560) prep_tile(P, 240 + s, lane);
    }
    gbar(P.bar, 0);

    // Phase 1: mlp (blocks 0..191) || prep d-weights + q2f (blocks 192..507)
    if (blk < 192) {
        mlp_body(P, smem, blk);
    } else {
        const int s = (blk - 192) * 4 + wv;           // 0..1279, need 1264
        if (s < 1264) prep_tile(P, (s < 240) ? s : 560 + s, lane);
    }
    gbar(P.bar, 1);

    // Phase 2: attention (one (b,d,hd) tile per block)
    attn_body(P, smem, blk);
    gbar(P.bar, 2);

    // Phase 3: dimwise net (1024 tiles of 32 points; 2 per block)
    dim_body(P, smem, blk * 2 + 0);
    __syncthreads();
    dim_body(P, smem, blk * 2 + 1);
}

extern "C" void kernel_launch(void* const* d_in, const int* in_sizes, int n_in,
                              void* d_out, int out_size, void* d_ws, size_t ws_size,
                              hipStream_t stream)
{
    typedef const float* fp;
    KParams P;
    P.t    = (fp)d_in[0];
    P.x    = (fp)d_in[1];
    P.q_w0 = (fp)d_in[2];  P.q_b0 = (fp)d_in[3];
    P.k_w0 = (fp)d_in[4];  P.k_b0 = (fp)d_in[5];
    P.v_w0 = (fp)d_in[6];  P.v_b0 = (fp)d_in[7];
    P.q_w1 = (fp)d_in[8];  P.q_b1 = (fp)d_in[9];
    P.k_w1 = (fp)d_in[10]; P.k_b1 = (fp)d_in[11];
    P.v_w1 = (fp)d_in[12]; P.v_b1 = (fp)d_in[13];
    P.q_w2 = (fp)d_in[14]; P.q_b2 = (fp)d_in[15];
    P.k_w2 = (fp)d_in[16]; P.k_b2 = (fp)d_in[17];
    P.v_w2 = (fp)d_in[18]; P.v_b2 = (fp)d_in[19];
    P.p_w  = (fp)d_in[20]; P.p_b  = (fp)d_in[21];
    P.d_w0 = (fp)d_in[22]; P.d_b0 = (fp)d_in[23];
    P.d_w1 = (fp)d_in[24]; P.d_b1 = (fp)d_in[25];
    P.d_w2 = (fp)d_in[26]; P.d_b2 = (fp)d_in[27];
    P.d_w3 = (fp)d_in[28]; P.d_b3 = (fp)d_in[29];

    __hip_bfloat16* wsb = (__hip_bfloat16*)d_ws;
    P.kbufF = wsb;                                   // 2048*128
    P.vbufF = P.kbufF + (size_t)kBN * kH;            // 2048*128
    P.obuf  = P.vbufF + (size_t)kBN * kH;            // 32768*128
    P.pwf   = P.obuf + (size_t)kP * kH;              // 8192
    P.w0f   = P.pwf + 8192;                          // 16384
    P.w1f   = P.w0f + 16384;                         // 65536
    P.w2f   = P.w1f + 65536;                         // 32768
    P.k0f   = P.w2f + 32768;                         // 8192
    P.v0f   = P.k0f + 8192;                          // 8192
    P.q0f   = P.v0f + 8192;                          // 8192
    P.k1f   = P.q0f + 8192;                          // 65536
    P.v1f   = P.k1f + 65536;                         // 65536
    P.q1f   = P.v1f + 65536;                         // 65536
    P.k2f   = P.q1f + 65536;                         // 32768
    P.v2f   = P.k2f + 32768;                         // 32768
    P.q2f   = P.v2f + 32768;                         // 524288
    P.h1qF  = P.q2f + 524288;                        // 2048*256 (A-frag packed)
    P.bar   = (unsigned*)((char*)d_ws + (size_t)(32 << 20));   // far past all buffers
    P.out   = (float*)d_out;

    init_kernel<<<1, 64, 0, stream>>>(P);
    fused_kernel<<<kGrid, 256, 0, stream>>>(P);
}

// Round 5
// 187.389 us; speedup vs baseline: 2.3137x; 2.3137x over previous
//
#include <hip/hip_runtime.h>
#include <hip/hip_bf16.h>

constexpr int kB = 8, kN = 256, kD = 16, kHID = 256, kH = 128, kDH = 64, kdh = 32;
constexpr int kBN = kB * kN;          // 2048 rows
constexpr int kP  = kBN * kD;         // 32768 points

__device__ __forceinline__ float b2f(__hip_bfloat16 v) { return __bfloat162float(v); }
__device__ __forceinline__ __hip_bfloat16 f2b(float v) { return __float2bfloat16(v); }
__device__ __forceinline__ unsigned short f2bs(float v) {
    __hip_bfloat16 h = __float2bfloat16(v);
    return *(unsigned short*)&h;
}

__device__ __forceinline__ float tanh_fast(float v) {
    float e = __expf(2.f * v);
    return 1.f - 2.f * __builtin_amdgcn_rcpf(e + 1.f);
}

typedef short s8v  __attribute__((ext_vector_type(8)));   // 8 bf16 = 4 VGPRs
typedef float f4v  __attribute__((ext_vector_type(4)));
#define MFMA(a, b, c) __builtin_amdgcn_mfma_f32_16x16x32_bf16((a), (b), (c), 0, 0, 0)

// ---------- Prep: swizzle ALL weights into MFMA B-fragment layout (bf16) ----------
__global__ __launch_bounds__(256) void prep_frag(
    const float* p_w, const float* d_w0, const float* d_w1, const float* d_w2,
    const float* k_w0, const float* k_w1, const float* k_w2,
    const float* v_w0, const float* v_w1, const float* v_w2,
    const float* q_w0, const float* q_w1, const float* q_w2,
    __hip_bfloat16* pwf, __hip_bfloat16* w0f, __hip_bfloat16* w1f, __hip_bfloat16* w2f,
    __hip_bfloat16* k0f, __hip_bfloat16* k1f, __hip_bfloat16* k2f,
    __hip_bfloat16* v0f, __hip_bfloat16* v1f, __hip_bfloat16* v2f,
    __hip_bfloat16* q0f, __hip_bfloat16* q1f, __hip_bfloat16* q2f)
{
    const int tile = blockIdx.x * 4 + (threadIdx.x >> 6);
    const int lane = threadIdx.x & 63;
    const float* src; __hip_bfloat16* dst; int N, NT, local, Kreal = 1 << 30, mask = 0;
    if (tile < 16)        { src = p_w;        dst = pwf; N = 64;   NT = 4;   local = tile; }
    else if (tile < 48)   { src = d_w0 + 512; dst = w0f; N = 256;  NT = 16;  local = tile - 16; }
    else if (tile < 176)  { src = d_w1;       dst = w1f; N = 256;  NT = 16;  local = tile - 48; }
    else if (tile < 240)  { src = d_w2;       dst = w2f; N = 128;  NT = 8;   local = tile - 176; }
    else if (tile < 256)  { src = k_w0;       dst = k0f; N = 256;  NT = 16;  local = tile - 240; Kreal = 16; }
    else if (tile < 272)  { src = v_w0;       dst = v0f; N = 256;  NT = 16;  local = tile - 256; Kreal = 16; }
    else if (tile < 288)  { src = q_w0;       dst = q0f; N = 256;  NT = 16;  local = tile - 272; Kreal = 16; mask = 1; }
    else if (tile < 416)  { src = k_w1;       dst = k1f; N = 256;  NT = 16;  local = tile - 288; }
    else if (tile < 544)  { src = v_w1;       dst = v1f; N = 256;  NT = 16;  local = tile - 416; }
    else if (tile < 672)  { src = q_w1;       dst = q1f; N = 256;  NT = 16;  local = tile - 544; mask = 2; }
    else if (tile < 736)  { src = k_w2;       dst = k2f; N = 128;  NT = 8;   local = tile - 672; }
    else if (tile < 800)  { src = v_w2;       dst = v2f; N = 128;  NT = 8;   local = tile - 736; }
    else                  { src = q_w2;       dst = q2f; N = 2048; NT = 128; local = tile - 800; mask = 3; }
    const int kt = local / NT, nt = local % NT;
    const int row0 = kt * 32 + (lane >> 4) * 8;
    const int col  = nt * 16 + (lane & 15);
    __hip_bfloat16* o = dst + ((size_t)local * 64 + lane) * 8;
    #pragma unroll
    for (int j = 0; j < 8; ++j) {
        const int r = row0 + j;
        float w = (r < Kreal) ? src[(size_t)r * N + col] : 0.f;
        if (mask == 1 && !((col % 15) >= r))        w = 0.f;
        if (mask == 2 && !((col % 15) >= (r % 15))) w = 0.f;
        if (mask == 3 && !((col >> 7) > (r % 15)))  w = 0.f;
        o[j] = f2b(w);
    }
}

// ---------- Kernel 1: MFMA MLPs, one path per block. grid = 64 row-tiles x 3 paths ----------
__global__ __launch_bounds__(256) void mlp_kernel(
    const float* x,
    const float* k_b0, const float* k_b1, const float* k_b2,
    const float* v_b0, const float* v_b1, const float* v_b2,
    const float* q_b0, const float* q_b1,
    const __hip_bfloat16* k0f, const __hip_bfloat16* k1f, const __hip_bfloat16* k2f,
    const __hip_bfloat16* v0f, const __hip_bfloat16* v1f, const __hip_bfloat16* v2f,
    const __hip_bfloat16* q0f, const __hip_bfloat16* q1f,
    __hip_bfloat16* kbufF, __hip_bfloat16* vbufF, __hip_bfloat16* h1qF)
{
    constexpr int SA = 264;
    constexpr int SX = 40;
    __shared__ __hip_bfloat16 xin[32 * SX];
    __shared__ __hip_bfloat16 bufA[32 * SA];
    __shared__ __hip_bfloat16 bufB[32 * SA];

    const int tid  = threadIdx.x;
    const int wv   = tid >> 6, lane = tid & 63;
    const int lx   = lane & 15, quad = lane >> 4;
    const int path = blockIdx.x >> 6;             // 0=k, 1=v, 2=q
    const int r0   = (blockIdx.x & 63) * 32;

    auto ldA = [&](const __hip_bfloat16* buf, int stride, int m0, int k0) -> s8v {
        return *(const s8v*)(buf + (m0 + lx) * stride + k0 + quad * 8);
    };
    auto ldB = [&](const __hip_bfloat16* wf, int NT, int kt, int nt) -> s8v {
        return *(const s8v*)(wf + (((size_t)(kt * NT + nt) * 64 + lane) << 3));
    };

    for (int idx = tid; idx < 1024; idx += 256) {
        const int row = idx >> 5, c = idx & 31;
        xin[row * SX + c] = f2b(c < 16 ? x[(r0 + row) * kD + c] : 0.f);
    }

    const __hip_bfloat16* F0[3] = { k0f, v0f, q0f };
    const __hip_bfloat16* F1[3] = { k1f, v1f, q1f };
    const __hip_bfloat16* F2[2] = { k2f, v2f };
    const float* Ba0[3] = { k_b0, v_b0, q_b0 };
    const float* Ba1[3] = { k_b1, v_b1, q_b1 };
    const float* Ba2[2] = { k_b2, v_b2 };

    __syncthreads();

    {   // L0: M=32, N=256, K=32 (padded)
        f4v acc[4][2] = {};
        const s8v a0 = ldA(xin, SX, 0, 0);
        const s8v a1 = ldA(xin, SX, 16, 0);
        #pragma unroll
        for (int j = 0; j < 4; ++j) {
            s8v b = ldB(F0[path], 16, 0, wv * 4 + j);
            acc[j][0] = MFMA(a0, b, acc[j][0]);
            acc[j][1] = MFMA(a1, b, acc[j][1]);
        }
        #pragma unroll
        for (int j = 0; j < 4; ++j) {
            const int n = (wv * 4 + j) * 16 + lx;
            const float bb = Ba0[path][n];
            #pragma unroll
            for (int mt = 0; mt < 2; ++mt)
            #pragma unroll
            for (int r = 0; r < 4; ++r) {
                const float v = acc[j][mt][r] + bb;
                const float z = (path == 2) ? fmaxf(v, 0.f) : tanh_fast(v);
                bufA[(mt * 16 + quad * 4 + r) * SA + n] = f2b(z);
            }
        }
    }
    __syncthreads();

    {   // L1: M=32, N=256, K=256
        f4v acc[4][2] = {};
        #pragma unroll
        for (int kt = 0; kt < 8; ++kt) {
            const s8v a0 = ldA(bufA, SA, 0, kt * 32);
            const s8v a1 = ldA(bufA, SA, 16, kt * 32);
            #pragma unroll
            for (int j = 0; j < 4; ++j) {
                s8v b = ldB(F1[path], 16, kt, wv * 4 + j);
                acc[j][0] = MFMA(a0, b, acc[j][0]);
                acc[j][1] = MFMA(a1, b, acc[j][1]);
            }
        }
        #pragma unroll
        for (int j = 0; j < 4; ++j) {
            const int n = (wv * 4 + j) * 16 + lx;
            const float bb = Ba1[path][n];
            #pragma unroll
            for (int mt = 0; mt < 2; ++mt)
            #pragma unroll
            for (int r = 0; r < 4; ++r) {
                const int m = mt * 16 + quad * 4 + r;
                const float v = acc[j][mt][r] + bb;
                if (path == 2) {
                    // A-fragment-packed h1q: tile = global_row>>4, lane' = ((n>>3)&3)*16 + (row&15)
                    const int kt2 = (wv * 4 + j) >> 1;
                    const int q2  = ((wv * 4 + j) & 1) * 2 + (lx >> 3);
                    h1qF[(size_t)(((r0 >> 4) + mt) * 8 + kt2) * 512
                         + (q2 * 16 + quad * 4 + r) * 8 + (lx & 7)] = f2b(fmaxf(v, 0.f));
                } else {
                    bufB[m * SA + n] = f2b(tanh_fast(v));
                }
            }
        }
    }
    if (path == 2) return;
    __syncthreads();

    {   // L2: M=32, N=128, K=256, linear -> fragment-packed kbufF / vbufF
        f4v acc[2][2] = {};
        #pragma unroll
        for (int kt = 0; kt < 8; ++kt) {
            const s8v a0 = ldA(bufB, SA, 0, kt * 32);
            const s8v a1 = ldA(bufB, SA, 16, kt * 32);
            #pragma unroll
            for (int j = 0; j < 2; ++j) {
                s8v b = ldB(F2[path], 8, kt, wv * 2 + j);
                acc[j][0] = MFMA(a0, b, acc[j][0]);
                acc[j][1] = MFMA(a1, b, acc[j][1]);
            }
        }
        const int bidx = r0 >> 8;
        const int ktv  = (r0 >> 5) & 7;
        #pragma unroll
        for (int j = 0; j < 2; ++j) {
            const int n  = (wv * 2 + j) * 16 + lx;
            const float bb = Ba2[path][n];
            const int hd = n >> 5;
            #pragma unroll
            for (int mt = 0; mt < 2; ++mt)
            #pragma unroll
            for (int r = 0; r < 4; ++r) {
                const int gr = r0 + mt * 16 + quad * 4 + r;
                const __hip_bfloat16 hv = f2b(acc[j][mt][r] + bb);
                if (path == 0) {
                    const int mtg = (gr >> 4) & 15;
                    kbufF[(size_t)(((bidx * 4 + hd) * 16 + mtg) * 64
                          + ((n & 31) >> 3) * 16 + (gr & 15)) * 8 + (lx & 7)] = hv;
                } else {
                    const int m5 = gr & 31;
                    vbufF[(size_t)((((bidx * 4 + hd) * 2 + ((n >> 4) & 1)) * 8 + ktv) * 64
                          + (m5 >> 3) * 16 + lx) * 8 + (m5 & 7)] = hv;
                }
            }
        }
    }
}

// ---------- Kernel 2: fused Q-projection + MFMA attention. 4 waves/block ----------
__global__ __launch_bounds__(256, 2) void attn_kernel(
    const float* q_b2, const __hip_bfloat16* h1qF, const __hip_bfloat16* q2f,
    const __hip_bfloat16* kbufF, const __hip_bfloat16* vbufF,
    __hip_bfloat16* obuf)
{
    constexpr int SP = 264;
    constexpr int QP = 40;                        // Q tile LDS stride (halves)
    __shared__ short Pl[4][16 * SP];              // 33.8 KB
    __shared__ short Qw[256 * QP];                // 20.0 KB

    const int blk = blockIdx.x;                   // b*64 + d*4 + hd
    const int hd = blk & 3;
    const int d  = (blk >> 2) & 15;
    const int b  = blk >> 6;

    const int wv   = threadIdx.x >> 6;            // query group (64 rows each)
    const int lane = threadIdx.x & 63;
    const int lx = lane & 15, quad = lane >> 4;
    short* Pw = &Pl[wv][0];

    const short* hq = (const short*)h1qF;
    const short* kb = (const short*)kbufF;
    const short* vb = (const short*)vbufF;
    const int bh = b * 4 + hd;

    // ---- fused Q-GEMM: M=64 (this wave's rows), N=32, K=256, all operands coalesced ----
    f4v qacc[4][2] = {};
    #pragma unroll
    for (int kt = 0; kt < 8; ++kt) {
        const s8v b0 = *(const s8v*)(q2f + (((size_t)(kt * 128 + d * 8 + hd * 2 + 0) * 64 + lane) << 3));
        const s8v b1 = *(const s8v*)(q2f + (((size_t)(kt * 128 + d * 8 + hd * 2 + 1) * 64 + lane) << 3));
        #pragma unroll
        for (int mt = 0; mt < 4; ++mt) {
            const s8v a = *(const s8v*)(hq + ((size_t)((b * 16 + wv * 4 + mt) * 8 + kt) * 512 + lane * 8));
            qacc[mt][0] = MFMA(a, b0, qacc[mt][0]);
            qacc[mt][1] = MFMA(a, b1, qacc[mt][1]);
        }
    }

    // K/V fragments: fully coalesced 16B/lane loads (issued early, consumed after barrier)
    s8v kfrag[16];
    #pragma unroll
    for (int mt = 0; mt < 16; ++mt)
        kfrag[mt] = *(const s8v*)(kb + ((size_t)(bh * 16 + mt) * 64 + lane) * 8);
    s8v vfrag[2][8];
    #pragma unroll
    for (int ntv = 0; ntv < 2; ++ntv)
    #pragma unroll
    for (int kt = 0; kt < 8; ++kt)
        vfrag[ntv][kt] = *(const s8v*)(vb + ((size_t)((bh * 2 + ntv) * 8 + kt) * 64 + lane) * 8);

    {   // Q epilogue: bias + 1/sqrt(dh) scale, store Q tile to LDS
        const float scale = 0.17677669529663687f;  // 1/sqrt(32)
        #pragma unroll
        for (int jn = 0; jn < 2; ++jn) {
            const float bb = q_b2[d * 128 + hd * 32 + jn * 16 + lx];
            #pragma unroll
            for (int mt = 0; mt < 4; ++mt)
            #pragma unroll
            for (int r = 0; r < 4; ++r) {
                const int lrow = wv * 64 + mt * 16 + quad * 4 + r;
                Qw[lrow * QP + jn * 16 + lx] = (short)f2bs((qacc[mt][jn][r] + bb) * scale);
            }
        }
    }
    __syncthreads();

    const float LOG2E = 1.4426950408889634f;

    for (int mi = 0; mi < 4; ++mi) {
        const int q0 = wv * 64 + mi * 16;

        const s8v qfrag = *(const s8v*)(Qw + (q0 + lx) * QP + quad * 8);

        f4v acc[16];
        #pragma unroll
        for (int mt = 0; mt < 16; ++mt) acc[mt] = f4v{0.f, 0.f, 0.f, 0.f};
        #pragma unroll
        for (int mt = 0; mt < 16; ++mt) acc[mt] = MFMA(kfrag[mt], qfrag, acc[mt]);

        const int qg = q0 + lx;
        float mx = -3.0e38f;
        #pragma unroll
        for (int mt = 0; mt < 16; ++mt)
        #pragma unroll
        for (int r = 0; r < 4; ++r) {
            const int key = mt * 16 + quad * 4 + r;
            float s = (key == qg) ? -3.0e38f : acc[mt][r];
            acc[mt][r] = s;
            mx = fmaxf(mx, s);
        }
        mx = fmaxf(mx, __shfl_xor(mx, 16, 64));
        mx = fmaxf(mx, __shfl_xor(mx, 32, 64));

        const float nmxc = -mx * LOG2E;
        float l = 0.f;
        #pragma unroll
        for (int mt = 0; mt < 16; ++mt)
        #pragma unroll
        for (int r = 0; r < 4; ++r) {
            float p = exp2f(__builtin_fmaf(acc[mt][r], LOG2E, nmxc));
            acc[mt][r] = p;
            l += p;
        }
        l += __shfl_xor(l, 16, 64);
        l += __shfl_xor(l, 32, 64);

        #pragma unroll
        for (int mt = 0; mt < 16; ++mt) {
            unsigned short h0 = f2bs(acc[mt][0]);
            unsigned short h1 = f2bs(acc[mt][1]);
            unsigned short h2 = f2bs(acc[mt][2]);
            unsigned short h3 = f2bs(acc[mt][3]);
            uint2 w;
            w.x = (unsigned int)h0 | ((unsigned int)h1 << 16);
            w.y = (unsigned int)h2 | ((unsigned int)h3 << 16);
            *(uint2*)(Pw + lx * SP + mt * 16 + quad * 4) = w;
        }
        __asm__ volatile("s_waitcnt lgkmcnt(0)" ::: "memory");

        f4v av[2] = { f4v{0.f,0.f,0.f,0.f}, f4v{0.f,0.f,0.f,0.f} };
        #pragma unroll
        for (int kt = 0; kt < 8; ++kt) {
            s8v a = *(const s8v*)(Pw + lx * SP + kt * 32 + quad * 8);
            av[0] = MFMA(a, vfrag[0][kt], av[0]);
            av[1] = MFMA(a, vfrag[1][kt], av[1]);
        }
        __asm__ volatile("s_waitcnt lgkmcnt(0)" ::: "memory");

        #pragma unroll
        for (int r = 0; r < 4; ++r) {
            const float lr = __shfl(l, quad * 4 + r, 64);
            const float inv = __builtin_amdgcn_rcpf(lr);
            const int qrow = q0 + quad * 4 + r;
            #pragma unroll
            for (int ntv = 0; ntv < 2; ++ntv) {
                obuf[((size_t)((b * 256 + qrow) * 16 + d)) * 128 + hd * 32 + ntv * 16 + lx]
                    = f2b(av[ntv][r] * inv);
            }
        }
    }
}

// ---------- Kernel 3: MFMA dimwise net. 16 points/block, 4 blocks/CU ----------
__global__ __launch_bounds__(256) void dim_kernel(
    const float* t, const float* x,
    const float* p_b, const float* d_w0, const float* d_b0,
    const float* d_b1, const float* d_b2, const float* d_w3, const float* d_b3,
    const __hip_bfloat16* pwf, const __hip_bfloat16* w0f,
    const __hip_bfloat16* w1f, const __hip_bfloat16* w2f,
    const __hip_bfloat16* obuf, float* out)
{
    constexpr int SA = 264;
    constexpr int SO = 136;
    constexpr int SH = 72;
    __shared__ __hip_bfloat16 bufA[32 * SA];   // 16.9 KB
    __shared__ __hip_bfloat16 bufB[32 * SA];   // 16.9 KB
    __shared__ __hip_bfloat16 bufH[16 * SH];   // 2.3 KB
    __shared__ float xvs[16];

    const int tid  = threadIdx.x;
    const int wv   = tid >> 6, lane = tid & 63;
    const int lx   = lane & 15, quad = lane >> 4;
    const int p0   = blockIdx.x * 16;
    const float tval = t[0];

    auto ldA = [&](const __hip_bfloat16* buf, int stride, int m0, int k0) -> s8v {
        return *(const s8v*)(buf + (m0 + lx) * stride + k0 + quad * 8);
    };
    auto ldBf = [&](const __hip_bfloat16* wf, int NT, int kt, int nt) -> s8v {
        return *(const s8v*)(wf + (((size_t)(kt * NT + nt) * 64 + lane) << 3));
    };

    // stage obuf rows (16 x 128) -> bufA stride SO
    for (int idx = tid; idx < 256; idx += 256) {
        const int row = idx >> 4, ch = idx & 15;
        *(f4v*)(bufA + row * SO + ch * 8) = *(const f4v*)(obuf + (size_t)(p0 + row) * kH + ch * 8);
    }
    if (tid < 16) xvs[tid] = x[p0 + tid];
    __syncthreads();

    {   // hfeat: M=16, N=64, K=128. wave -> N-tile wv. read bufA -> write bufH
        f4v acc0 = {};
        #pragma unroll
        for (int ktile = 0; ktile < 4; ++ktile) {
            s8v b  = ldBf(pwf, 4, ktile, wv);
            s8v a0 = ldA(bufA, SO, 0, ktile * 32);
            acc0 = MFMA(a0, b, acc0);
        }
        const int n = wv * 16 + lx;
        const float bb = p_b[n];
        #pragma unroll
        for (int r = 0; r < 4; ++r)
            bufH[(quad * 4 + r) * SH + n] = f2b(acc0[r] + bb);
    }
    __syncthreads();

    {   // L0: M=16, N=256, K=64. read bufH -> write bufB (z rows 0-15, zd rows 16-31)
        f4v acc[4] = {};
        #pragma unroll
        for (int ktile = 0; ktile < 2; ++ktile) {
            s8v a0 = ldA(bufH, SH, 0, ktile * 32);
            #pragma unroll
            for (int j = 0; j < 4; ++j) {
                s8v b = ldBf(w0f, 16, ktile, wv * 4 + j);
                acc[j] = MFMA(a0, b, acc[j]);
            }
        }
        #pragma unroll
        for (int j = 0; j < 4; ++j) {
            const int n = (wv * 4 + j) * 16 + lx;
            const float base = d_b0[n] + tval * d_w0[n];
            const float wx   = d_w0[256 + n];
            #pragma unroll
            for (int r = 0; r < 4; ++r) {
                const int m = quad * 4 + r;
                const float z = tanh_fast(acc[j][r] + base + xvs[m] * wx);
                bufB[m * SA + n]        = f2b(z);
                bufB[(m + 16) * SA + n] = f2b((1.f - z * z) * wx);
            }
        }
    }
    __syncthreads();

    {   // L1: M=32 (16 fwd + 16 tgt), N=256, K=256. read bufB -> write bufA
        f4v acc[4][2] = {};
        #pragma unroll
        for (int ktile = 0; ktile < 8; ++ktile) {
            s8v a0 = ldA(bufB, SA, 0,  ktile * 32);
            s8v a1 = ldA(bufB, SA, 16, ktile * 32);
            #pragma unroll
            for (int j = 0; j < 4; ++j) {
                s8v b = ldBf(w1f, 16, ktile, wv * 4 + j);
                acc[j][0] = MFMA(a0, b, acc[j][0]);
                acc[j][1] = MFMA(a1, b, acc[j][1]);
            }
        }
        #pragma unroll
        for (int j = 0; j < 4; ++j) {
            const int n = (wv * 4 + j) * 16 + lx;
            const float b1 = d_b1[n];
            #pragma unroll
            for (int r = 0; r < 4; ++r) {
                const int m = quad * 4 + r;
                const float z  = tanh_fast(acc[j][0][r] + b1);
                const float zd = (1.f - z * z) * acc[j][1][r];
                bufA[m * SA + n]        = f2b(z);
                bufA[(m + 16) * SA + n] = f2b(zd);
            }
        }
    }
    __syncthreads();

    {   // L2: M=32, N=128, K=256. read bufA -> write bufB (stride SO)
        f4v acc[2][2] = {};
        #pragma unroll
        for (int ktile = 0; ktile < 8; ++ktile) {
            s8v a0 = ldA(bufA, SA, 0,  ktile * 32);
            s8v a1 = ldA(bufA, SA, 16, ktile * 32);
            #pragma unroll
            for (int j = 0; j < 2; ++j) {
                s8v b = ldBf(w2f, 8, ktile, wv * 2 + j);
                acc[j][0] = MFMA(a0, b, acc[j][0]);
                acc[j][1] = MFMA(a1, b, acc[j][1]);
            }
        }
        #pragma unroll
        for (int j = 0; j < 2; ++j) {
            const int n = (wv * 2 + j) * 16 + lx;
            const float b2 = d_b2[n];
            #pragma unroll
            for (int r = 0; r < 4; ++r) {
                const int m = quad * 4 + r;
                const float z  = tanh_fast(acc[j][0][r] + b2);
                const float zd = (1.f - z * z) * acc[j][1][r];
                bufB[m * SO + n]        = f2b(z);
                bufB[(m + 16) * SO + n] = f2b(zd);
            }
        }
    }
    __syncthreads();

    {   // L3 reduce: 16 points x 16 threads, 8 cols each
        const int p = tid >> 4, s = tid & 15;
        float yv = 0.f, jv = 0.f;
        #pragma unroll
        for (int i = 0; i < 8; ++i) {
            const int n = s + i * 16;
            const float w = d_w3[n];
            yv += b2f(bufB[p * SO + n]) * w;
            jv += b2f(bufB[(p + 16) * SO + n]) * w;
        }
        #pragma unroll
        for (int off = 8; off > 0; off >>= 1) {
            yv += __shfl_down(yv, off, 16);
            jv += __shfl_down(jv, off, 16);
        }
        if (s == 0) {
            out[p0 + p]      = yv + d_b3[0];
            out[kP + p0 + p] = jv;
        }
    }
}

extern "C" void kernel_launch(void* const* d_in, const int* in_sizes, int n_in,
                              void* d_out, int out_size, void* d_ws, size_t ws_size,
                              hipStream_t stream)
{
    typedef const float* fp;
    fp t    = (fp)d_in[0];
    fp x    = (fp)d_in[1];
    fp q_w0 = (fp)d_in[2],  q_b0 = (fp)d_in[3];
    fp k_w0 = (fp)d_in[4],  k_b0 = (fp)d_in[5];
    fp v_w0 = (fp)d_in[6],  v_b0 = (fp)d_in[7];
    fp q_w1 = (fp)d_in[8],  q_b1 = (fp)d_in[9];
    fp k_w1 = (fp)d_in[10], k_b1 = (fp)d_in[11];
    fp v_w1 = (fp)d_in[12], v_b1 = (fp)d_in[13];
    fp q_w2 = (fp)d_in[14], q_b2 = (fp)d_in[15];
    fp k_w2 = (fp)d_in[16], k_b2 = (fp)d_in[17];
    fp v_w2 = (fp)d_in[18], v_b2 = (fp)d_in[19];
    fp p_w  = (fp)d_in[20], p_b  = (fp)d_in[21];
    fp d_w0 = (fp)d_in[22], d_b0 = (fp)d_in[23];
    fp d_w1 = (fp)d_in[24], d_b1 = (fp)d_in[25];
    fp d_w2 = (fp)d_in[26], d_b2 = (fp)d_in[27];
    fp d_w3 = (fp)d_in[28], d_b3 = (fp)d_in[29];

    __hip_bfloat16* wsb   = (__hip_bfloat16*)d_ws;
    __hip_bfloat16* kbufF = wsb;                                 // 2048*128
    __hip_bfloat16* vbufF = kbufF + (size_t)kBN * kH;            // 2048*128
    __hip_bfloat16* obuf  = vbufF + (size_t)kBN * kH;            // 32768*128
    __hip_bfloat16* pwf   = obuf + (size_t)kP * kH;              // 8192
    __hip_bfloat16* w0f   = pwf + 8192;                          // 16384
    __hip_bfloat16* w1f   = w0f + 16384;                         // 65536
    __hip_bfloat16* w2f   = w1f + 65536;                         // 32768
    __hip_bfloat16* k0f   = w2f + 32768;                         // 8192
    __hip_bfloat16* v0f   = k0f + 8192;                          // 8192
    __hip_bfloat16* q0f   = v0f + 8192;                          // 8192
    __hip_bfloat16* k1f   = q0f + 8192;                          // 65536
    __hip_bfloat16* v1f   = k1f + 65536;                         // 65536
    __hip_bfloat16* q1f   = v1f + 65536;                         // 65536
    __hip_bfloat16* k2f   = q1f + 65536;                         // 32768
    __hip_bfloat16* v2f   = k2f + 32768;                         // 32768
    __hip_bfloat16* q2f   = v2f + 32768;                         // 524288
    __hip_bfloat16* h1qF  = q2f + 524288;                        // 2048*256 (A-frag packed)

    float* out = (float*)d_out;

    prep_frag<<<456, 256, 0, stream>>>(p_w, d_w0, d_w1, d_w2,
        k_w0, k_w1, k_w2, v_w0, v_w1, v_w2, q_w0, q_w1, q_w2,
        pwf, w0f, w1f, w2f, k0f, k1f, k2f, v0f, v1f, v2f, q0f, q1f, q2f);
    mlp_kernel<<<192, 256, 0, stream>>>(x,
        k_b0, k_b1, k_b2, v_b0, v_b1, v_b2, q_b0, q_b1,
        k0f, k1f, k2f, v0f, v1f, v2f, q0f, q1f, kbufF, vbufF, h1qF);
    attn_kernel<<<kB * kD * 4, 256, 0, stream>>>(q_b2, h1qF, q2f, kbufF, vbufF, obuf);
    dim_kernel<<<kP / 16, 256, 0, stream>>>(t, x, p_b, d_w0, d_b0, d_b1, d_b2, d_w3, d_b3,
        pwf, w0f, w1f, w2f, obuf, out);
}